// Round 4
// baseline (92.456 us; speedup 1.0000x reference)
//
#include <hip/hip_runtime.h>

// YOLO v1 loss, fp32. preds/labels: [B, 7, 7, 30] fp32. Output: scalar fp32.
// 2 cells per thread -> 15 aligned float4 loads per array, no LDS, no syncs
// in the hot path. Deterministic last-block final reduction (fixed tree order).

#define LAMBDA_COORD 5.0f
#define LAMBDA_NOOBJ 0.5f

__device__ __forceinline__ float iou_xywh(const float* b1, const float* b2) {
    float b1x1 = b1[0] - b1[2] * 0.5f;
    float b1y1 = b1[1] - b1[3] * 0.5f;
    float b1x2 = b1[0] + b1[2] * 0.5f;
    float b1y2 = b1[1] + b1[3] * 0.5f;
    float b2x1 = b2[0] - b2[2] * 0.5f;
    float b2y1 = b2[1] - b2[3] * 0.5f;
    float b2x2 = b2[0] + b2[2] * 0.5f;
    float b2y2 = b2[1] + b2[3] * 0.5f;
    float iw = fmaxf(fminf(b1x2, b2x2) - fmaxf(b1x1, b2x1), 0.0f);
    float ih = fmaxf(fminf(b1y2, b2y2) - fmaxf(b1y1, b2y1), 0.0f);
    float inter = iw * ih;
    float area1 = (b1x2 - b1x1) * (b1y2 - b1y1);
    float area2 = (b2x2 - b2x1) * (b2y2 - b2y1);
    return inter / (area1 + area2 - inter + 1e-10f);
}

__device__ __forceinline__ float cell_loss(const float* __restrict__ p,
                                           const float* __restrict__ l) {
    bool obj  = (l[4] == 1.0f);
    float iou1 = iou_xywh(p + 0, l + 0);
    float iou2 = iou_xywh(p + 5, l + 0);
    bool box1 = (iou1 > iou2);

    float dx1 = l[0] - p[0], dy1 = l[1] - p[1];
    float xy1 = dx1 * dx1 + dy1 * dy1;
    float dx2 = l[5] - p[5], dy2 = l[6] - p[6];
    float xy2 = dx2 * dx2 + dy2 * dy2;

    float dw1 = sqrtf(l[2]) - sqrtf(p[2]);
    float dh1 = sqrtf(l[3]) - sqrtf(p[3]);
    float wh1 = dw1 * dw1 + dh1 * dh1;
    float dw2 = sqrtf(l[7]) - sqrtf(p[7]);
    float dh2 = sqrtf(l[8]) - sqrtf(p[8]);
    float wh2 = dw2 * dw2 + dh2 * dh2;

    float dc1 = l[4] - p[4];
    float conf1 = dc1 * dc1;
    float dc2 = l[9] - p[9];
    float conf2 = dc2 * dc2;

    float cls = 0.0f;
    #pragma unroll
    for (int k = 10; k < 30; ++k) {
        float d = l[k] - p[k];
        cls = fmaf(d, d, cls);
    }

    if (obj) {
        float xy  = box1 ? xy1 : xy2;
        float wh  = box1 ? wh1 : wh2;
        float cf  = box1 ? conf1 : conf2;
        float no  = box1 ? p[9] * p[9] : p[4] * p[4];
        return LAMBDA_COORD * (xy + wh) + cf + LAMBDA_NOOBJ * no + cls;
    } else {
        return LAMBDA_NOOBJ * (p[4] * p[4] + p[9] * p[9]);
    }
}

__device__ __forceinline__ float block_reduce_sum(float v, float* smem) {
    #pragma unroll
    for (int off = 32; off > 0; off >>= 1)
        v += __shfl_down(v, off, 64);
    int lane = threadIdx.x & 63;
    int wid  = threadIdx.x >> 6;
    if (lane == 0) smem[wid] = v;
    __syncthreads();
    float total = 0.0f;
    if (threadIdx.x == 0) {
        int nw = blockDim.x >> 6;
        for (int i = 0; i < nw; ++i) total += smem[i];
    }
    return total;  // valid only on thread 0
}

__global__ void __launch_bounds__(256) yolo_loss(
        const float* __restrict__ preds,
        const float* __restrict__ labels,
        float* __restrict__ out,
        float* __restrict__ partial,
        unsigned int* __restrict__ counter,
        int npairs, int ncells, float inv_batch) {
    __shared__ float smem[4];
    __shared__ float smem2[4];
    __shared__ int is_last;

    int tid = threadIdx.x;
    float acc = 0.0f;
    int stride = gridDim.x * blockDim.x;

    for (int pi = blockIdx.x * blockDim.x + tid; pi < npairs; pi += stride) {
        // pair pi = cells 2pi, 2pi+1; base byte = pi*240 -> 16B aligned
        const float4* gp = reinterpret_cast<const float4*>(preds)  + (size_t)pi * 15;
        const float4* gl = reinterpret_cast<const float4*>(labels) + (size_t)pi * 15;
        float4 P[15], L[15];
        #pragma unroll
        for (int i = 0; i < 15; ++i) P[i] = gp[i];
        #pragma unroll
        for (int i = 0; i < 15; ++i) L[i] = gl[i];
        const float* pf = reinterpret_cast<const float*>(P);
        const float* lf = reinterpret_cast<const float*>(L);
        acc += cell_loss(pf, lf) + cell_loss(pf + 30, lf + 30);
    }

    // odd-cell tail (not hit for B*49 even, kept for generality)
    if ((ncells & 1) && blockIdx.x == 0 && tid == 0) {
        const float* p = preds  + (size_t)(ncells - 1) * 30;
        const float* l = labels + (size_t)(ncells - 1) * 30;
        float pbuf[30], lbuf[30];
        for (int i = 0; i < 30; ++i) { pbuf[i] = p[i]; lbuf[i] = l[i]; }
        acc += cell_loss(pbuf, lbuf);
    }

    float bsum = block_reduce_sum(acc, smem);
    if (tid == 0) {
        partial[blockIdx.x] = bsum;
        __threadfence();                                   // make partial visible device-wide
        unsigned int prev = atomicAdd(counter, 1u);
        is_last = (prev == gridDim.x - 1) ? 1 : 0;
    }
    __syncthreads();

    if (is_last) {
        __threadfence();                                   // acquire partials
        float a = 0.0f;
        for (int i = tid; i < (int)gridDim.x; i += blockDim.x)
            a += partial[i];                               // fixed order -> deterministic
        float total = block_reduce_sum(a, smem2);
        if (tid == 0) out[0] = total * inv_batch;
    }
}

extern "C" void kernel_launch(void* const* d_in, const int* in_sizes, int n_in,
                              void* d_out, int out_size, void* d_ws, size_t ws_size,
                              hipStream_t stream) {
    const float* preds  = (const float*)d_in[0];
    const float* labels = (const float*)d_in[1];
    float* out = (float*)d_out;

    int ncells = in_sizes[0] / 30;            // B * 7 * 7
    int npairs = ncells >> 1;                 // 401408 at B=16384
    int batch  = ncells / 49;
    float inv_batch = 1.0f / (float)batch;

    const int block = 256;
    int grid = (npairs + block - 1) / block;  // 1568 at B=16384: one pair/thread
    int maxblocks = (int)((ws_size - sizeof(unsigned int)) / sizeof(float));
    if (grid > maxblocks) grid = maxblocks;   // grid-stride covers the rest
    if (grid > 2048) grid = 2048;
    if (grid < 1) grid = 1;

    float* partial = (float*)d_ws;
    unsigned int* counter = (unsigned int*)((char*)d_ws + (size_t)grid * sizeof(float));

    hipMemsetAsync(counter, 0, sizeof(unsigned int), stream);
    yolo_loss<<<grid, block, 0, stream>>>(preds, labels, out, partial, counter,
                                          npairs, ncells, inv_batch);
}